// Round 5
// baseline (776.997 us; speedup 1.0000x reference)
//
#include <hip/hip_runtime.h>
#include <hip/hip_fp16.h>

typedef _Float16 f16;
typedef _Float16 f16x8 __attribute__((ext_vector_type(8)));
typedef _Float16 f16x4 __attribute__((ext_vector_type(4)));
typedef float    f32x4 __attribute__((ext_vector_type(4)));

#define AS1 __attribute__((address_space(1)))
#define AS3 __attribute__((address_space(3)))

// async 16B global->LDS DMA: global addr is per-lane, LDS dest is
// wave-uniform base + lane*16 (m104/m108) -- LDS side must be linear.
__device__ __forceinline__ void gl_lds16(const void* g, void* l) {
    __builtin_amdgcn_global_load_lds((const AS1 unsigned int*)g,
                                     (AS3 unsigned int*)l, 16, 0, 0);
}

#define NB   8
#define NN   32
#define NT   64
#define ND   64
#define NK   4
#define NH   256
#define NSO  256
#define NE   992
#define TOUT 63
#define M1   (NB*TOUT*NN)   // 16128 node-time rows

// ---- workspace layout (bytes) ----
static constexpr size_t SZ_RS   = (size_t)M1 * 1024 * 2;        // 33,030,144 (f16, [m][k*256+h])
static constexpr size_t OFF_R   = 0;
static constexpr size_t OFF_S   = OFF_R + SZ_RS;
static constexpr size_t OFF_W2T = OFF_S + SZ_RS;                // f16 [k][co][h] chunk-swizzled
static constexpr size_t OFF_WF1 = OFF_W2T + 4*256*256*2;        // f16 [co][d(320)] 163,840
static constexpr size_t OFF_WF2 = OFF_WF1 + 256*320*2;          // f16 [co][h]      131,072
static constexpr size_t OFF_WF3 = OFF_WF2 + 256*256*2;          // f16 [d][h]        32,768
static constexpr size_t OFF_REL = OFF_WF3 + 64*256*2;           // f32 [b][ns][k][32] 131,072
static constexpr size_t OFF_AGG = OFF_REL + (size_t)NB*NN*NK*32*4; // f32 [m][256]  16,515,072
// W1T (f16 [c(2048)][d(64)], 262,144 B) overlaps the AGG region: k0 writes it,
// k1 consumes it, k2 overwrites AGG afterwards (stream-ordered, safe).
// total = 83,558,400 bytes

// ============================ K0: weight prep ============================
__global__ __launch_bounds__(256) void k0_prep(
    const float* __restrict__ W1, const float* __restrict__ W2,
    const float* __restrict__ Wf1, const float* __restrict__ Wf2,
    const float* __restrict__ Wf3, const float* __restrict__ rel,
    f16* __restrict__ W1T, f16* __restrict__ W2S, f16* __restrict__ Wf1T,
    f16* __restrict__ Wf2T, f16* __restrict__ Wf3T, float* __restrict__ REL)
{
    int id = blockIdx.x * 256 + threadIdx.x;
    if (id < 262144) {
        // W2S[k][co][hc*64 + c*8 + e] = W2[k][hc*64 + (c^(co&7))*8 + e][co]
        // (16B chunks of each 64-col sub-row pre-swizzled by co&7 for DMA staging)
        int k = id >> 16, co = (id >> 8) & 255, h = id & 255;
        int hc = h >> 6, c = (h >> 3) & 7, e = h & 7;
        int hl = hc*64 + ((c ^ (co & 7)) << 3) + e;
        W2S[id] = (f16)W2[k*65536 + hl*256 + co];
    } else if (id < 344064) {               // Wf1T[co][d] = Wf1[d][co], d<320
        int i = id - 262144; int co = i / 320, d = i % 320;
        Wf1T[i] = (f16)Wf1[d*256 + co];
    } else if (id < 409600) {               // Wf2T[co][h] = Wf2[h][co]
        int i = id - 344064; int co = i >> 8, h = i & 255;
        Wf2T[i] = (f16)Wf2[h*256 + co];
    } else if (id < 425984) {               // Wf3T[d][h] = Wf3[h][d], d<64
        int i = id - 409600; int d = i >> 8, h = i & 255;
        Wf3T[i] = (f16)Wf3[h*64 + d];
    } else if (id < 458752) {               // REL[b][ns][k][j], self-edge -> 0
        int i = id - 425984;
        int j = i & 31, k = (i >> 5) & 3, ns = (i >> 7) & 31, b = i >> 12;
        float v = 0.f;
        if (j != ns) v = rel[(b*NE + ns*31 + (j < ns ? j : j - 1))*NK + k];
        REL[i] = v;
    } else {                                // W1T[c][d] = W1[k][dd*64+d][h], c=k*512+dd*256+h
        int i = id - 458752;
        int c = i >> 6, d = i & 63;
        int k = c >> 9, dd = (c >> 8) & 1, h = c & 255;
        W1T[i] = (f16)W1[(k*128 + dd*64 + d)*NH + h];
    }
}

// ============ K1: per-node layer-1 partials R,S (MFMA, f16) ============
// Output Rb/Sb with each 64-f16 sub-block's 16B chunks swizzled by n&7
// (n = node index = m&31), so k2's linear DMA staging lands pre-swizzled.
__global__ __launch_bounds__(256) void k1_partials(
    const float* __restrict__ inputs, const f16* __restrict__ W1T,
    const float* __restrict__ b1, f16* __restrict__ Rb, f16* __restrict__ Sb)
{
    __shared__ __align__(16) f16 xs[64][72];     // A: 64 rows x 64 d
    __shared__ __align__(16) f16 wl[256][72];    // B: 256 cols x 64 d; reused as out-stage
    int tid = threadIdx.x;
    int w = tid >> 6, lane = tid & 63, ln = lane & 15, q = lane >> 4;
    int m0 = blockIdx.x * 64;

    #pragma unroll
    for (int it = 0; it < 2; ++it) {             // stage x -> f16
        int idx8 = it*256 + tid;
        int m = idx8 >> 3, hs = idx8 & 7;
        int mrow = m0 + m;
        int b = mrow / 2016, r2 = mrow % 2016, t = r2 >> 5, n = r2 & 31;
        const float* px = &inputs[((b*NN + n)*NT + t)*ND + hs*8];
        f32x4 v0 = *(const f32x4*)px, v1 = *(const f32x4*)(px + 4);
        f16x8 o;
        #pragma unroll
        for (int e = 0; e < 4; ++e) { o[e] = (f16)v0[e]; o[e+4] = (f16)v1[e]; }
        *(f16x8*)&xs[m][hs*8] = o;
    }
    const f32x4 z4 = {0.f, 0.f, 0.f, 0.f};
    for (int cc = 0; cc < 8; ++cc) {             // 8 chunks of 256 output cols
        int k = cc >> 1, dd = cc & 1;
        __syncthreads();
        #pragma unroll
        for (int it = 0; it < 8; ++it) {         // stage W1T chunk
            int idx8 = it*256 + tid;
            int co = idx8 >> 3, seg = idx8 & 7;
            *(f16x8*)&wl[co][seg*8] = *(const f16x8*)&W1T[(size_t)(cc*256 + co)*64 + seg*8];
        }
        __syncthreads();
        f32x4 acc[16];
        #pragma unroll
        for (int nt = 0; nt < 16; ++nt) acc[nt] = z4;
        #pragma unroll
        for (int ks = 0; ks < 2; ++ks) {
            f16x8 Af = *(const f16x8*)&xs[w*16 + ln][ks*32 + q*8];
            #pragma unroll
            for (int nt = 0; nt < 16; ++nt) {
                f16x8 Bf = *(const f16x8*)&wl[nt*16 + ln][ks*32 + q*8];
                acc[nt] = __builtin_amdgcn_mfma_f32_16x16x32_f16(Af, Bf, acc[nt], 0, 0, 0);
            }
        }
        __syncthreads();                          // wl now reusable as out staging
        f16* ob = &wl[0][0];                      // 64 rows x 256 cols, stride 264
        #pragma unroll
        for (int nt = 0; nt < 16; ++nt) {
            int co = nt*16 + ln;
            float bias = dd ? b1[k*NH + co] : 0.f;
            #pragma unroll
            for (int r = 0; r < 4; ++r) {
                float v = acc[nt][r] + bias;
                ob[(w*16 + q*4 + r)*264 + co] = (f16)v;
            }
        }
        __syncthreads();
        f16* dst = dd ? Sb : Rb;
        #pragma unroll
        for (int it = 0; it < 8; ++it) {          // swizzled coalesced stores
            int idx8 = it*256 + tid;
            int m = idx8 >> 5, seg = idx8 & 31;   // n = (m0+m)&31 = m&31
            int hcb = seg >> 3, c = seg & 7;
            *(f16x8*)&dst[(size_t)(m0 + m)*1024 + k*256 + hcb*64 + c*8] =
                *(const f16x8*)&ob[m*264 + hcb*64 + (((c ^ (m & 7))) << 3)];
        }
    }
}

// ============ K2: fused edge MLP layer-2 + mixture + sender-aggregate ============
// Block = (b, t, ns-quad): M = 128 rows = 4 senders x 32 receivers, N = 256.
// Staging is pure global_load_lds DMA (16B/lane): 1KB per wave-call, LDS linear;
// data arrives pre-swizzled (chunk ^ row&7) from k0/k1 so MFMA-side ds_read_b128
// at pos (chunk^(ln&7)) is 2-way-conflict-free (free per m136).
// __launch_bounds__(512,4): 128-reg cap. NEVER (512,6) -- 85-reg cap forces the
// 64-reg accumulator to spill to scratch (round-3: 10.7 GB HBM, 4x regression).
__global__ __launch_bounds__(512, 4) void k2_edge(
    const f16* __restrict__ Rb, const f16* __restrict__ Sb,
    const f16* __restrict__ W2S, const float* __restrict__ b2,
    const float* __restrict__ REL, float* __restrict__ AGG)
{
    __shared__ __align__(16) f16 rs[40*64];      // rows 0-31 R(j); 32-35 S(nsl); 36-39 dup
    __shared__ __align__(16) f16 w2c[256*64];    // [co][8 chunks], data pre-swizzled
    __shared__ __align__(16) float agg_s[4*256];
    int tid = threadIdx.x;
    int blk = blockIdx.x;
    int b = blk & 7, r0 = blk >> 3, nsq = r0 & 7, t = r0 >> 3;   // t in [0,63)
    int w = tid >> 6, lane = tid & 63, ln = lane & 15, q = lane >> 4;
    int mg = w >> 2, ng = w & 3;
    size_t bt = (size_t)(b*TOUT + t);

    agg_s[tid] = 0.f;
    agg_s[512 + tid] = 0.f;

    // per-lane DMA source geometry
    int lrow = lane >> 3, lc = lane & 7;         // 8 rows x 8 chunks per 1KB call
    int srow = w*8 + lrow;                       // rs row for waves 0-4
    size_t g_rs;                                 // global row base for rs staging
    if (srow < 32) g_rs = (bt*NN + srow)*1024;
    else           g_rs = (bt*NN + nsq*4 + ((srow - 32) & 3))*1024;
    const f16* rs_src = (srow < 32) ? Rb : Sb;

    const f32x4 z4 = {0.f, 0.f, 0.f, 0.f};
    f32x4 acc[4][4];
    for (int k = 0; k < 4; ++k) {
        #pragma unroll
        for (int mt = 0; mt < 4; ++mt)
            #pragma unroll
            for (int nt = 0; nt < 4; ++nt) acc[mt][nt] = z4;

        for (int hc = 0; hc < 4; ++hc) {
            __syncthreads();                     // prev round's LDS reads done
            // rs: waves 0-4 DMA 8 rows each (R rows 0-31, S rows 32-35 +dup)
            if (w < 5)
                gl_lds16(&rs_src[g_rs + k*256 + hc*64 + lc*8],
                         &rs[(w*8)*64 + lane*8]);
            // w2c: 8 waves x 4 calls of 1KB (8 co-rows each)
            #pragma unroll
            for (int it = 0; it < 4; ++it) {
                int co0 = (it*8 + w)*8;
                gl_lds16(&W2S[(size_t)(k*256 + co0 + lrow)*256 + hc*64 + lc*8],
                         &w2c[co0*64 + lane*8]);
            }
            __syncthreads();                     // drains vmcnt (DMA complete)
            #pragma unroll
            for (int ks = 0; ks < 2; ++ks) {
                int Kc = ks*4 + q;               // logical 16B chunk 0..7
                int pa = (Kc ^ (ln & 7)) << 3;   // de-swizzled read offset (f16)
                f16x8 s0 = *(const f16x8*)&rs[(32 + mg*2 + 0)*64 +
                                ((Kc ^ ((nsq*4 + mg*2 + 0) & 7)) << 3)];
                f16x8 s1 = *(const f16x8*)&rs[(32 + mg*2 + 1)*64 +
                                ((Kc ^ ((nsq*4 + mg*2 + 1) & 7)) << 3)];
                f16x8 rlo = *(const f16x8*)&rs[ln*64 + pa];
                f16x8 rhi = *(const f16x8*)&rs[(16 + ln)*64 + pa];
                f16x8 A[4];
                #pragma unroll
                for (int mt = 0; mt < 4; ++mt) {
                    f16x8 rr = (mt & 1) ? rhi : rlo;
                    f16x8 ss = (mt >> 1) ? s1 : s0;
                    f16x8 v;
                    #pragma unroll
                    for (int e = 0; e < 8; ++e) {
                        f16 x = rr[e] + ss[e];
                        v[e] = x > (f16)0 ? x : (f16)0;
                    }
                    A[mt] = v;
                }
                #pragma unroll
                for (int nt = 0; nt < 4; ++nt) {
                    f16x8 Bf = *(const f16x8*)&w2c[(ng*64 + nt*16 + ln)*64 + pa];
                    #pragma unroll
                    for (int mt = 0; mt < 4; ++mt)
                        acc[mt][nt] = __builtin_amdgcn_mfma_f32_16x16x32_f16(
                            A[mt], Bf, acc[mt][nt], 0, 0, 0);
                }
            }
        }
        // epilogue for mixture k: bias+relu, scale by rel, reduce 32 j -> agg
        #pragma unroll
        for (int mt = 0; mt < 4; ++mt) {
            int nsl = mg*2 + (mt >> 1);
            int nsg = nsq*4 + nsl;
            int j0 = (mt & 1)*16 + q*4;
            f32x4 relv = *(const f32x4*)&REL[((b*NN + nsg)*NK + k)*32 + j0];
            #pragma unroll
            for (int nt = 0; nt < 4; ++nt) {
                int co = ng*64 + nt*16 + ln;
                float bias = b2[k*NSO + co];
                float s = 0.f;
                #pragma unroll
                for (int r = 0; r < 4; ++r) {
                    float v = acc[mt][nt][r] + bias;
                    v = v > 0.f ? v : 0.f;
                    s += v * relv[r];
                }
                s += __shfl_xor(s, 16);
                s += __shfl_xor(s, 32);
                if (lane < 16) agg_s[nsl*256 + ng*64 + nt*16 + lane] += s;
            }
        }
    }
    __syncthreads();
    #pragma unroll
    for (int it = 0; it < 2; ++it) {
        int idx = it*512 + tid;
        int nsl = idx >> 8, co = idx & 255;
        AGG[(bt*NN + nsq*4 + nsl)*NSO + co] = agg_s[idx];
    }
}

// ============ K3: node MLP (320->256->256->64) + residual ============
__global__ __launch_bounds__(256) void k3_node(
    const float* __restrict__ inputs, const float* __restrict__ AGG,
    const f16* __restrict__ Wf1T, const float* __restrict__ bf1,
    const f16* __restrict__ Wf2T, const float* __restrict__ bf2,
    const f16* __restrict__ Wf3T, const float* __restrict__ bf3,
    float* __restrict__ out)
{
    __shared__ __align__(16) f16 aug[64][328];   // [x(64) | agg(256)] + pad
    __shared__ __align__(16) f16 p1[64][264];
    __shared__ __align__(16) f16 wl[256][72];
    int tid = threadIdx.x;
    int w = tid >> 6, lane = tid & 63, ln = lane & 15, q = lane >> 4;
    int m0 = blockIdx.x * 64;

    for (int it = 0; it < 10; ++it) {       // stage aug
        int s = it*256 + tid;
        if (s < 512) {
            int m = s >> 3, hs = s & 7;
            int mrow = m0 + m;
            int b = mrow / 2016, r2 = mrow % 2016, t = r2 >> 5, n = r2 & 31;
            const float* px = &inputs[((b*NN + n)*NT + t)*ND + hs*8];
            f32x4 v0 = *(const f32x4*)px, v1 = *(const f32x4*)(px + 4);
            f16x8 o;
            #pragma unroll
            for (int e = 0; e < 4; ++e) { o[e] = (f16)v0[e]; o[e+4] = (f16)v1[e]; }
            *(f16x8*)&aug[m][hs*8] = o;
        } else {
            int s2 = s - 512;
            int m = s2 >> 5, hs = s2 & 31;
            const float* pa = &AGG[(size_t)(m0 + m)*NSO + hs*8];
            f32x4 v0 = *(const f32x4*)pa, v1 = *(const f32x4*)(pa + 4);
            f16x8 o;
            #pragma unroll
            for (int e = 0; e < 4; ++e) { o[e] = (f16)v0[e]; o[e+4] = (f16)v1[e]; }
            *(f16x8*)&aug[m][64 + hs*8] = o;
        }
    }
    const f32x4 z4 = {0.f, 0.f, 0.f, 0.f};
    // ---- layer 1: K=320 ----
    f32x4 acc1[16];
    #pragma unroll
    for (int nt = 0; nt < 16; ++nt) acc1[nt] = z4;
    for (int hc = 0; hc < 5; ++hc) {
        __syncthreads();
        #pragma unroll
        for (int it = 0; it < 8; ++it) {
            int idx8 = it*256 + tid;
            int co = idx8 >> 3, seg = idx8 & 7;
            *(f16x8*)&wl[co][seg*8] = *(const f16x8*)&Wf1T[co*320 + hc*64 + seg*8];
        }
        __syncthreads();
        #pragma unroll
        for (int ks = 0; ks < 2; ++ks) {
            f16x8 Af = *(const f16x8*)&aug[w*16 + ln][hc*64 + ks*32 + q*8];
            #pragma unroll
            for (int nt = 0; nt < 16; ++nt) {
                f16x8 Bf = *(const f16x8*)&wl[nt*16 + ln][ks*32 + q*8];
                acc1[nt] = __builtin_amdgcn_mfma_f32_16x16x32_f16(Af, Bf, acc1[nt], 0, 0, 0);
            }
        }
    }
    #pragma unroll
    for (int nt = 0; nt < 16; ++nt) {
        int co = nt*16 + ln;
        float bias = bf1[co];
        #pragma unroll
        for (int r = 0; r < 4; ++r) {
            float v = acc1[nt][r] + bias; v = v > 0.f ? v : 0.f;
            p1[w*16 + q*4 + r][co] = (f16)v;
        }
    }
    // ---- layer 2: K=256 ----
    f32x4 acc2[16];
    #pragma unroll
    for (int nt = 0; nt < 16; ++nt) acc2[nt] = z4;
    for (int hc = 0; hc < 4; ++hc) {
        __syncthreads();
        #pragma unroll
        for (int it = 0; it < 8; ++it) {
            int idx8 = it*256 + tid;
            int co = idx8 >> 3, seg = idx8 & 7;
            *(f16x8*)&wl[co][seg*8] = *(const f16x8*)&Wf2T[co*256 + hc*64 + seg*8];
        }
        __syncthreads();
        #pragma unroll
        for (int ks = 0; ks < 2; ++ks) {
            f16x8 Af = *(const f16x8*)&p1[w*16 + ln][hc*64 + ks*32 + q*8];
            #pragma unroll
            for (int nt = 0; nt < 16; ++nt) {
                f16x8 Bf = *(const f16x8*)&wl[nt*16 + ln][ks*32 + q*8];
                acc2[nt] = __builtin_amdgcn_mfma_f32_16x16x32_f16(Af, Bf, acc2[nt], 0, 0, 0);
            }
        }
    }
    f16* p2 = &aug[0][0];    // reuse aug storage, stride 264
    #pragma unroll
    for (int nt = 0; nt < 16; ++nt) {
        int co = nt*16 + ln;
        float bias = bf2[co];
        #pragma unroll
        for (int r = 0; r < 4; ++r) {
            float v = acc2[nt][r] + bias; v = v > 0.f ? v : 0.f;
            p2[(w*16 + q*4 + r)*264 + co] = (f16)v;
        }
    }
    __syncthreads();
    // ---- layer 3: K=256, N=64 ----
    f16* w3 = &wl[0][0];     // reuse wl storage, stride 264
    #pragma unroll
    for (int it = 0; it < 8; ++it) {
        int idx8 = it*256 + tid;
        int d = idx8 >> 5, seg = idx8 & 31;
        *(f16x8*)&w3[d*264 + seg*8] = *(const f16x8*)&Wf3T[d*256 + seg*8];
    }
    __syncthreads();
    f32x4 acc3[4];
    #pragma unroll
    for (int nt = 0; nt < 4; ++nt) acc3[nt] = z4;
    #pragma unroll
    for (int ks = 0; ks < 8; ++ks) {
        f16x8 Af = *(const f16x8*)&p2[(w*16 + ln)*264 + ks*32 + q*8];
        #pragma unroll
        for (int nt = 0; nt < 4; ++nt) {
            f16x8 Bf = *(const f16x8*)&w3[(nt*16 + ln)*264 + ks*32 + q*8];
            acc3[nt] = __builtin_amdgcn_mfma_f32_16x16x32_f16(Af, Bf, acc3[nt], 0, 0, 0);
        }
    }
    #pragma unroll
    for (int nt = 0; nt < 4; ++nt) {
        int d = nt*16 + ln;
        float bias = bf3[d];
        #pragma unroll
        for (int r = 0; r < 4; ++r) {
            int mrow = m0 + w*16 + q*4 + r;
            int b = mrow / 2016, r2 = mrow % 2016, t = r2 >> 5, n = r2 & 31;
            float xv = inputs[((b*NN + n)*NT + t)*ND + d];
            out[((size_t)(b*NN + n)*TOUT + t)*ND + d] = acc3[nt][r] + bias + xv;
        }
    }
}

extern "C" void kernel_launch(void* const* d_in, const int* in_sizes, int n_in,
                              void* d_out, int out_size, void* d_ws, size_t ws_size,
                              hipStream_t stream)
{
    const float* inputs = (const float*)d_in[0];
    const float* rel    = (const float*)d_in[1];
    const float* W1     = (const float*)d_in[4];
    const float* b1     = (const float*)d_in[5];
    const float* W2     = (const float*)d_in[6];
    const float* b2     = (const float*)d_in[7];
    const float* Wf1    = (const float*)d_in[8];
    const float* bf1    = (const float*)d_in[9];
    const float* Wf2    = (const float*)d_in[10];
    const float* bf2    = (const float*)d_in[11];
    const float* Wf3    = (const float*)d_in[12];
    const float* bf3    = (const float*)d_in[13];
    char* ws = (char*)d_ws;
    f16*   Rb   = (f16*)(ws + OFF_R);
    f16*   Sb   = (f16*)(ws + OFF_S);
    f16*   W2S  = (f16*)(ws + OFF_W2T);
    f16*   Wf1T = (f16*)(ws + OFF_WF1);
    f16*   Wf2T = (f16*)(ws + OFF_WF2);
    f16*   Wf3T = (f16*)(ws + OFF_WF3);
    float* REL  = (float*)(ws + OFF_REL);
    float* AGG  = (float*)(ws + OFF_AGG);
    f16*   W1T  = (f16*)(ws + OFF_AGG);   // overlaps AGG; consumed before k2 writes AGG
    float* out  = (float*)d_out;

    hipLaunchKernelGGL(k0_prep, dim3(2304), dim3(256), 0, stream,
                       W1, W2, Wf1, Wf2, Wf3, rel, W1T, W2S, Wf1T, Wf2T, Wf3T, REL);
    hipLaunchKernelGGL(k1_partials, dim3(252), dim3(256), 0, stream,
                       inputs, W1T, b1, Rb, Sb);
    hipLaunchKernelGGL(k2_edge, dim3(4032), dim3(512), 0, stream,
                       Rb, Sb, W2S, b2, REL, AGG);
    hipLaunchKernelGGL(k3_node, dim3(252), dim3(256), 0, stream,
                       inputs, AGG, Wf1T, bf1, Wf2T, bf2, Wf3T, bf3, out);
}

// Round 7
// 458.244 us; speedup vs baseline: 1.6956x; 1.6956x over previous
//
#include <hip/hip_runtime.h>
#include <hip/hip_fp16.h>

typedef _Float16 f16;
typedef _Float16 f16x8 __attribute__((ext_vector_type(8)));
typedef _Float16 f16x4 __attribute__((ext_vector_type(4)));
typedef float    f32x4 __attribute__((ext_vector_type(4)));

#define AS1 __attribute__((address_space(1)))
#define AS3 __attribute__((address_space(3)))

// async 16B global->LDS DMA: LDS dest is wave-uniform base + lane*16.
__device__ __forceinline__ void gl_lds16(const void* g, void* l) {
    __builtin_amdgcn_global_load_lds((const AS1 unsigned int*)g,
                                     (AS3 unsigned int*)l, 16, 0, 0);
}

#define NB   8
#define NN   32
#define NT   64
#define ND   64
#define NK   4
#define NH   256
#define NSO  256
#define NE   992
#define TOUT 63
#define M1   (NB*TOUT*NN)   // 16128 node-time rows
#define NBT  (NB*TOUT)      // 504 (b,t) pairs

// ---- workspace layout (bytes) ----
static constexpr size_t SZ_RS   = (size_t)M1 * 1024 * 2;        // 33,030,144
static constexpr size_t OFF_R   = 0;
static constexpr size_t OFF_S   = OFF_R + SZ_RS;
static constexpr size_t OFF_W2T = OFF_S + SZ_RS;                // f16 [k][co][h] 524,288
static constexpr size_t OFF_WF1 = OFF_W2T + 4*256*256*2;        // f16 [co][d(320)]
static constexpr size_t OFF_WF2 = OFF_WF1 + 256*320*2;
static constexpr size_t OFF_WF3 = OFF_WF2 + 256*256*2;
static constexpr size_t OFF_REL = OFF_WF3 + 64*256*2;           // f32 [b][ns][k][32]
static constexpr size_t OFF_AGG = OFF_REL + (size_t)NB*NN*NK*32*4; // f32 [m][256] 16,515,072
static constexpr size_t OFF_W1T = OFF_AGG + (size_t)M1*256*4;   // f16 [c(2048)][d(64)]
// total = OFF_W1T + 262,144 = 83,820,544 bytes

// ============================ K0: weight prep + AGG zero ============================
__global__ __launch_bounds__(256) void k0_prep(
    const float* __restrict__ W1, const float* __restrict__ W2,
    const float* __restrict__ Wf1, const float* __restrict__ Wf2,
    const float* __restrict__ Wf3, const float* __restrict__ rel,
    f16* __restrict__ W1T, f16* __restrict__ W2T, f16* __restrict__ Wf1T,
    f16* __restrict__ Wf2T, f16* __restrict__ Wf3T, float* __restrict__ REL,
    unsigned int* __restrict__ AGGZ)
{
    int id = blockIdx.x * 256 + threadIdx.x;
    if (id < 262144) {                      // W2T[k][co][h] = W2[k][h][co]
        int k = id >> 16, co = (id >> 8) & 255, h = id & 255;
        W2T[id] = (f16)W2[k*65536 + h*256 + co];
    } else if (id < 344064) {               // Wf1T[co][d] = Wf1[d][co], d<320
        int i = id - 262144; int co = i / 320, d = i % 320;
        Wf1T[i] = (f16)Wf1[d*256 + co];
    } else if (id < 409600) {               // Wf2T[co][h] = Wf2[h][co]
        int i = id - 344064; int co = i >> 8, h = i & 255;
        Wf2T[i] = (f16)Wf2[h*256 + co];
    } else if (id < 425984) {               // Wf3T[d][h] = Wf3[h][d], d<64
        int i = id - 409600; int d = i >> 8, h = i & 255;
        Wf3T[i] = (f16)Wf3[h*64 + d];
    } else if (id < 458752) {               // REL[b][ns][k][j], self-edge -> 0
        int i = id - 425984;
        int j = i & 31, k = (i >> 5) & 3, ns = (i >> 7) & 31, b = i >> 12;
        float v = 0.f;
        if (j != ns) v = rel[(b*NE + ns*31 + (j < ns ? j : j - 1))*NK + k];
        REL[i] = v;
    } else {                                // W1T[c][d] = W1[k][dd*64+d][h] (131072 elems)
        int i = id - 458752;
        int c = i >> 6, d = i & 63;
        int k = c >> 9, dd = (c >> 8) & 1, h = c & 255;
        W1T[i] = (f16)W1[(k*128 + dd*64 + d)*NH + h];
    }
    // zero AGG (f32): 4,128,768 dwords = 7 x 589,824 threads exactly
    #pragma unroll
    for (int j = 0; j < 7; ++j) {
        int idx = id + j*589824;
        if (idx < 4128768) AGGZ[idx] = 0u;
    }
}

// ============ K1: per-node layer-1 partials R,S (MFMA, f16) ============
// Rb/Sb rows stored with each 64-f16 sub-block's 16B chunks swizzled by n&7
// (n = node = m&31) so k2's LDS reads at chunk^(row&7) are conflict-free.
__global__ __launch_bounds__(256) void k1_partials(
    const float* __restrict__ inputs, const f16* __restrict__ W1T,
    const float* __restrict__ b1, f16* __restrict__ Rb, f16* __restrict__ Sb)
{
    __shared__ __align__(16) f16 xs[64][72];
    __shared__ __align__(16) f16 wl[256][72];
    int tid = threadIdx.x;
    int w = tid >> 6, lane = tid & 63, ln = lane & 15, q = lane >> 4;
    int m0 = blockIdx.x * 64;

    #pragma unroll
    for (int it = 0; it < 2; ++it) {             // stage x -> f16
        int idx8 = it*256 + tid;
        int m = idx8 >> 3, hs = idx8 & 7;
        int mrow = m0 + m;
        int b = mrow / 2016, r2 = mrow % 2016, t = r2 >> 5, n = r2 & 31;
        const float* px = &inputs[((b*NN + n)*NT + t)*ND + hs*8];
        f32x4 v0 = *(const f32x4*)px, v1 = *(const f32x4*)(px + 4);
        f16x8 o;
        #pragma unroll
        for (int e = 0; e < 4; ++e) { o[e] = (f16)v0[e]; o[e+4] = (f16)v1[e]; }
        *(f16x8*)&xs[m][hs*8] = o;
    }
    const f32x4 z4 = {0.f, 0.f, 0.f, 0.f};
    for (int cc = 0; cc < 8; ++cc) {             // 8 chunks of 256 output cols
        int k = cc >> 1, dd = cc & 1;
        __syncthreads();
        #pragma unroll
        for (int it = 0; it < 8; ++it) {
            int idx8 = it*256 + tid;
            int co = idx8 >> 3, seg = idx8 & 7;
            *(f16x8*)&wl[co][seg*8] = *(const f16x8*)&W1T[(size_t)(cc*256 + co)*64 + seg*8];
        }
        __syncthreads();
        f32x4 acc[16];
        #pragma unroll
        for (int nt = 0; nt < 16; ++nt) acc[nt] = z4;
        #pragma unroll
        for (int ks = 0; ks < 2; ++ks) {
            f16x8 Af = *(const f16x8*)&xs[w*16 + ln][ks*32 + q*8];
            #pragma unroll
            for (int nt = 0; nt < 16; ++nt) {
                f16x8 Bf = *(const f16x8*)&wl[nt*16 + ln][ks*32 + q*8];
                acc[nt] = __builtin_amdgcn_mfma_f32_16x16x32_f16(Af, Bf, acc[nt], 0, 0, 0);
            }
        }
        __syncthreads();
        f16* ob = &wl[0][0];                      // out-stage, stride 264
        #pragma unroll
        for (int nt = 0; nt < 16; ++nt) {
            int co = nt*16 + ln;
            float bias = dd ? b1[k*NH + co] : 0.f;
            #pragma unroll
            for (int r = 0; r < 4; ++r) {
                float v = acc[nt][r] + bias;
                ob[(w*16 + q*4 + r)*264 + co] = (f16)v;
            }
        }
        __syncthreads();
        f16* dst = dd ? Sb : Rb;
        #pragma unroll
        for (int it = 0; it < 8; ++it) {          // swizzled coalesced stores
            int idx8 = it*256 + tid;
            int m = idx8 >> 5, seg = idx8 & 31;
            int hcb = seg >> 3, c = seg & 7;
            *(f16x8*)&dst[(size_t)(m0 + m)*1024 + k*256 + hcb*64 + c*8] =
                *(const f16x8*)&ob[m*264 + hcb*64 + (((c ^ (m & 7))) << 3)];
        }
    }
}

// ============ K2: edge MLP layer-2, W2 resident in REGISTERS ============
// Block = (k, bt-chunk of 8): grid 252, 512 thr, ~1 block/CU.
// Per lane: B-frags for its 4 col-tiles x K=256 = 128 VGPR, loaded once.
// LDS: R dbuf (2x16KB, reused by 8 nsq tiles) + S dbuf (2x2KB) via DMA.
// k fixed per block -> mixture sum via device-scope f32 atomicAdd into AGG.
__global__ __launch_bounds__(512, 2) void k2_edge(
    const f16* __restrict__ Rb, const f16* __restrict__ Sb,
    const f16* __restrict__ W2T, const float* __restrict__ b2,
    const float* __restrict__ REL, float* __restrict__ AGG)
{
    __shared__ __align__(16) f16 Rbuf[2][32*256];
    __shared__ __align__(16) f16 Sbuf[2][4*256];
    int tid = threadIdx.x;
    int blk = blockIdx.x;
    int k = blk & 3, g = blk >> 2;               // g in 0..62 -> bt = g*8..g*8+7
    int w = tid >> 6, lane = tid & 63, ln = lane & 15, q = lane >> 4;
    int mg = w >> 2, ng = w & 3;
    int lrow = lane >> 5, lseg = lane & 31;      // DMA: 2 rows x 32 chunks per call

    // ---- W2(k) fragments in registers + bias ----
    f16x8 Breg[4][8];
    float bias[4];
    #pragma unroll
    for (int nt = 0; nt < 4; ++nt) {
        int co = ng*64 + nt*16 + ln;
        bias[nt] = b2[k*256 + co];
        const f16* wrow = &W2T[(size_t)(k*256 + co)*256];
        #pragma unroll
        for (int ks = 0; ks < 8; ++ks)
            Breg[nt][ks] = *(const f16x8*)&wrow[ks*32 + q*8];
    }

    auto stageR = [&](int bt, int buf) {         // 16 KB: 16 calls (2/wave)
        #pragma unroll
        for (int it = 0; it < 2; ++it) {
            int rowbase = (w*2 + it)*2;
            gl_lds16(&Rb[((size_t)bt*NN + rowbase + lrow)*1024 + k*256 + lseg*8],
                     &Rbuf[buf][rowbase*256 + lane*8]);
        }
    };
    auto stageS = [&](int i, int buf) {          // 2 KB: 2 calls (waves 0,1)
        int bt = g*8 + (i >> 3), nsq = i & 7;
        if (w < 2)
            gl_lds16(&Sb[((size_t)bt*NN + nsq*4 + w*2 + lrow)*1024 + k*256 + lseg*8],
                     &Sbuf[buf][(w*2)*256 + lane*8]);
    };

    stageR(g*8, 0);
    stageS(0, 0);
    __syncthreads();

    const f32x4 z4 = {0.f, 0.f, 0.f, 0.f};
    for (int i = 0; i < 64; ++i) {
        int ibt = i >> 3, nsq = i & 7;
        int bt = g*8 + ibt, b = bt / TOUT;
        int rb = ibt & 1, sb = i & 1;
        if (i < 63) stageS(i + 1, sb ^ 1);
        if (nsq == 6 && ibt < 7) stageR(bt + 1, rb ^ 1);

        const f16* Rl = &Rbuf[rb][0];
        const f16* Sl = &Sbuf[sb][0];
        int ns0 = nsq*4 + mg*2;                  // this wave's first sender
        f32x4 acc[4][4];
        #pragma unroll
        for (int mt = 0; mt < 4; ++mt)
            #pragma unroll
            for (int nt = 0; nt < 4; ++nt) acc[mt][nt] = z4;

        #pragma unroll
        for (int ks = 0; ks < 8; ++ks) {
            int hc = ks >> 1;
            int c4 = (ks & 1)*4 + q;
            int paR = hc*64 + ((c4 ^ (ln & 7)) << 3);
            f16x8 rlo = *(const f16x8*)&Rl[ln*256 + paR];
            f16x8 rhi = *(const f16x8*)&Rl[(16 + ln)*256 + paR];
            f16x8 s0 = *(const f16x8*)&Sl[(mg*2 + 0)*256 + hc*64 + ((c4 ^ (ns0 & 7)) << 3)];
            f16x8 s1 = *(const f16x8*)&Sl[(mg*2 + 1)*256 + hc*64 + ((c4 ^ ((ns0 + 1) & 7)) << 3)];
            f16x8 A[4];
            #pragma unroll
            for (int mt = 0; mt < 4; ++mt) {
                f16x8 rr = (mt & 1) ? rhi : rlo;
                f16x8 ss = (mt >> 1) ? s1 : s0;
                f16x8 v;
                #pragma unroll
                for (int e = 0; e < 8; ++e) {
                    f16 x = rr[e] + ss[e];
                    v[e] = x > (f16)0 ? x : (f16)0;
                }
                A[mt] = v;
            }
            #pragma unroll
            for (int nt = 0; nt < 4; ++nt) {
                f16x8 Bf = Breg[nt][ks];
                #pragma unroll
                for (int mt = 0; mt < 4; ++mt)
                    acc[mt][nt] = __builtin_amdgcn_mfma_f32_16x16x32_f16(
                        A[mt], Bf, acc[mt][nt], 0, 0, 0);
            }
        }
        // epilogue: bias+relu, rel-weight, reduce over 32 j, f32 atomic add
        #pragma unroll
        for (int half = 0; half < 2; ++half) {
            int ns = ns0 + half;
            const float* relp = &REL[(((size_t)b*NN + ns)*NK + k)*32];
            f32x4 rel0 = *(const f32x4*)&relp[q*4];
            f32x4 rel1 = *(const f32x4*)&relp[16 + q*4];
            #pragma unroll
            for (int nt = 0; nt < 4; ++nt) {
                float s = 0.f;
                #pragma unroll
                for (int r = 0; r < 4; ++r) {
                    float v0 = acc[2*half + 0][nt][r] + bias[nt];
                    float v1 = acc[2*half + 1][nt][r] + bias[nt];
                    v0 = v0 > 0.f ? v0 : 0.f;
                    v1 = v1 > 0.f ? v1 : 0.f;
                    s += v0 * rel0[r] + v1 * rel1[r];
                }
                s += __shfl_xor(s, 16);
                s += __shfl_xor(s, 32);
                if (lane < 16)
                    atomicAdd(&AGG[((size_t)bt*NN + ns)*256 + ng*64 + nt*16 + lane], s);
            }
        }
        __syncthreads();
    }
}

// ============ K3: node MLP (320->256->256->64) + residual ============
__global__ __launch_bounds__(256) void k3_node(
    const float* __restrict__ inputs, const float* __restrict__ AGG,
    const f16* __restrict__ Wf1T, const float* __restrict__ bf1,
    const f16* __restrict__ Wf2T, const float* __restrict__ bf2,
    const f16* __restrict__ Wf3T, const float* __restrict__ bf3,
    float* __restrict__ out)
{
    __shared__ __align__(16) f16 aug[64][328];
    __shared__ __align__(16) f16 p1[64][264];
    __shared__ __align__(16) f16 wl[256][72];
    int tid = threadIdx.x;
    int w = tid >> 6, lane = tid & 63, ln = lane & 15, q = lane >> 4;
    int m0 = blockIdx.x * 64;

    for (int it = 0; it < 10; ++it) {       // stage aug = [x | agg]
        int s = it*256 + tid;
        if (s < 512) {
            int m = s >> 3, hs = s & 7;
            int mrow = m0 + m;
            int b = mrow / 2016, r2 = mrow % 2016, t = r2 >> 5, n = r2 & 31;
            const float* px = &inputs[((b*NN + n)*NT + t)*ND + hs*8];
            f32x4 v0 = *(const f32x4*)px, v1 = *(const f32x4*)(px + 4);
            f16x8 o;
            #pragma unroll
            for (int e = 0; e < 4; ++e) { o[e] = (f16)v0[e]; o[e+4] = (f16)v1[e]; }
            *(f16x8*)&aug[m][hs*8] = o;
        } else {
            int s2 = s - 512;
            int m = s2 >> 5, hs = s2 & 31;
            const float* pa = &AGG[(size_t)(m0 + m)*NSO + hs*8];
            f32x4 v0 = *(const f32x4*)pa, v1 = *(const f32x4*)(pa + 4);
            f16x8 o;
            #pragma unroll
            for (int e = 0; e < 4; ++e) { o[e] = (f16)v0[e]; o[e+4] = (f16)v1[e]; }
            *(f16x8*)&aug[m][64 + hs*8] = o;
        }
    }
    const f32x4 z4 = {0.f, 0.f, 0.f, 0.f};
    // ---- layer 1: K=320 ----
    f32x4 acc1[16];
    #pragma unroll
    for (int nt = 0; nt < 16; ++nt) acc1[nt] = z4;
    for (int hc = 0; hc < 5; ++hc) {
        __syncthreads();
        #pragma unroll
        for (int it = 0; it < 8; ++it) {
            int idx8 = it*256 + tid;
            int co = idx8 >> 3, seg = idx8 & 7;
            *(f16x8*)&wl[co][seg*8] = *(const f16x8*)&Wf1T[co*320 + hc*64 + seg*8];
        }
        __syncthreads();
        #pragma unroll
        for (int ks = 0; ks < 2; ++ks) {
            f16x8 Af = *(const f16x8*)&aug[w*16 + ln][hc*64 + ks*32 + q*8];
            #pragma unroll
            for (int nt = 0; nt < 16; ++nt) {
                f16x8 Bf = *(const f16x8*)&wl[nt*16 + ln][ks*32 + q*8];
                acc1[nt] = __builtin_amdgcn_mfma_f32_16x16x32_f16(Af, Bf, acc1[nt], 0, 0, 0);
            }
        }
    }
    #pragma unroll
    for (int nt = 0; nt < 16; ++nt) {
        int co = nt*16 + ln;
        float bias = bf1[co];
        #pragma unroll
        for (int r = 0; r < 4; ++r) {
            float v = acc1[nt][r] + bias; v = v > 0.f ? v : 0.f;
            p1[w*16 + q*4 + r][co] = (f16)v;
        }
    }
    // ---- layer 2: K=256 ----
    f32x4 acc2[16];
    #pragma unroll
    for (int nt = 0; nt < 16; ++nt) acc2[nt] = z4;
    for (int hc = 0; hc < 4; ++hc) {
        __syncthreads();
        #pragma unroll
        for (int it = 0; it < 8; ++it) {
            int idx8 = it*256 + tid;
            int co = idx8 >> 3, seg = idx8 & 7;
            *(f16x8*)&wl[co][seg*8] = *(const f16x8*)&Wf2T[co*256 + hc*64 + seg*8];
        }
        __syncthreads();
        #pragma unroll
        for (int ks = 0; ks < 2; ++ks) {
            f16x8 Af = *(const f16x8*)&p1[w*16 + ln][hc*64 + ks*32 + q*8];
            #pragma unroll
            for (int nt = 0; nt < 16; ++nt) {
                f16x8 Bf = *(const f16x8*)&wl[nt*16 + ln][ks*32 + q*8];
                acc2[nt] = __builtin_amdgcn_mfma_f32_16x16x32_f16(Af, Bf, acc2[nt], 0, 0, 0);
            }
        }
    }
    f16* p2 = &aug[0][0];    // reuse aug storage, stride 264
    #pragma unroll
    for (int nt = 0; nt < 16; ++nt) {
        int co = nt*16 + ln;
        float bias = bf2[co];
        #pragma unroll
        for (int r = 0; r < 4; ++r) {
            float v = acc2[nt][r] + bias; v = v > 0.f ? v : 0.f;
            p2[(w*16 + q*4 + r)*264 + co] = (f16)v;
        }
    }
    __syncthreads();
    // ---- layer 3: K=256, N=64 ----
    f16* w3 = &wl[0][0];
    #pragma unroll
    for (int it = 0; it < 8; ++it) {
        int idx8 = it*256 + tid;
        int d = idx8 >> 5, seg = idx8 & 31;
        *(f16x8*)&w3[d*264 + seg*8] = *(const f16x8*)&Wf3T[d*256 + seg*8];
    }
    __syncthreads();
    f32x4 acc3[4];
    #pragma unroll
    for (int nt = 0; nt < 4; ++nt) acc3[nt] = z4;
    #pragma unroll
    for (int ks = 0; ks < 8; ++ks) {
        f16x8 Af = *(const f16x8*)&p2[(w*16 + ln)*264 + ks*32 + q*8];
        #pragma unroll
        for (int nt = 0; nt < 4; ++nt) {
            f16x8 Bf = *(const f16x8*)&w3[(nt*16 + ln)*264 + ks*32 + q*8];
            acc3[nt] = __builtin_amdgcn_mfma_f32_16x16x32_f16(Af, Bf, acc3[nt], 0, 0, 0);
        }
    }
    #pragma unroll
    for (int nt = 0; nt < 4; ++nt) {
        int d = nt*16 + ln;
        float bias = bf3[d];
        #pragma unroll
        for (int r = 0; r < 4; ++r) {
            int mrow = m0 + w*16 + q*4 + r;
            int b = mrow / 2016, r2 = mrow % 2016, t = r2 >> 5, n = r2 & 31;
            float xv = inputs[((b*NN + n)*NT + t)*ND + d];
            out[((size_t)(b*NN + n)*TOUT + t)*ND + d] = acc3[nt][r] + bias + xv;
        }
    }
}

extern "C" void kernel_launch(void* const* d_in, const int* in_sizes, int n_in,
                              void* d_out, int out_size, void* d_ws, size_t ws_size,
                              hipStream_t stream)
{
    const float* inputs = (const float*)d_in[0];
    const float* rel    = (const float*)d_in[1];
    const float* W1     = (const float*)d_in[4];
    const float* b1     = (const float*)d_in[5];
    const float* W2     = (const float*)d_in[6];
    const float* b2     = (const float*)d_in[7];
    const float* Wf1    = (const float*)d_in[8];
    const float* bf1    = (const float*)d_in[9];
    const float* Wf2    = (const float*)d_in[10];
    const float* bf2    = (const float*)d_in[11];
    const float* Wf3    = (const float*)d_in[12];
    const float* bf3    = (const float*)d_in[13];
    char* ws = (char*)d_ws;
    f16*   Rb   = (f16*)(ws + OFF_R);
    f16*   Sb   = (f16*)(ws + OFF_S);
    f16*   W2T  = (f16*)(ws + OFF_W2T);
    f16*   Wf1T = (f16*)(ws + OFF_WF1);
    f16*   Wf2T = (f16*)(ws + OFF_WF2);
    f16*   Wf3T = (f16*)(ws + OFF_WF3);
    float* REL  = (float*)(ws + OFF_REL);
    float* AGG  = (float*)(ws + OFF_AGG);
    f16*   W1T  = (f16*)(ws + OFF_W1T);
    float* out  = (float*)d_out;

    hipLaunchKernelGGL(k0_prep, dim3(2304), dim3(256), 0, stream,
                       W1, W2, Wf1, Wf2, Wf3, rel, W1T, W2T, Wf1T, Wf2T, Wf3T, REL,
                       (unsigned int*)AGG);
    hipLaunchKernelGGL(k1_partials, dim3(252), dim3(256), 0, stream,
                       inputs, W1T, b1, Rb, Sb);
    hipLaunchKernelGGL(k2_edge, dim3(252), dim3(512), 0, stream,
                       Rb, Sb, W2T, b2, REL, AGG);
    hipLaunchKernelGGL(k3_node, dim3(252), dim3(256), 0, stream,
                       inputs, AGG, Wf1T, bf1, Wf2T, bf2, Wf3T, bf3, out);
}